// Round 3
// baseline (147.602 us; speedup 1.0000x reference)
//
#include <hip/hip_runtime.h>
#include <hip/hip_bf16.h>
#include <stdint.h>

// KAN layer fused: out[b,o] = sum_{i,k} basis(tanh(x[b,i]))[k] * coeffs[o,i,k]
// GEMM M=8192, N=512, K=4096 with A (basis) computed IN-KERNEL per tile:
// a lane's 16x16x32 A-frag (8 bf16, k = quad*8+j) == one (b,i) pair's 8 basis
// slots, so 4 basis evals/thread + 1 ds_write_b128 build the A-tile. No A in
// HBM/ws -> no ws chunking (ws = Bt 4MB only). In-block split-K: 512 thr =
// 2 K-groups x 4 waves, per-group dbuf LDS arena, LDS reduction epilogue.

#define M_TOTAL 8192
#define N_DIM   512
#define K_DIM   4096
#define BM 128
#define BN 128
#define BK 64
#define NT_HALF 32          // K-tiles per K-group (2048/64)
#define GRP_LDS 65536       // per-group arena (2 buffers)
#define BUF_HALF 32768      // one buffer: A 16KB + B 16KB

typedef __attribute__((ext_vector_type(8))) short short8;   // 8 x bf16
typedef __attribute__((ext_vector_type(4))) float f32x4;

typedef const __attribute__((address_space(1))) uint32_t ga_u32;
typedef __attribute__((address_space(3))) uint32_t ls_u32;

__device__ __forceinline__ void gload_lds16(const void* g, void* l) {
  __builtin_amdgcn_global_load_lds((ga_u32*)(uintptr_t)g,
                                   (ls_u32*)(uint32_t)(uintptr_t)l, 16, 0, 0);
}

__device__ __forceinline__ uint32_t f2bf(float f) {
  uint32_t u = __builtin_bit_cast(uint32_t, f);
  return (u + 0x7FFFu + ((u >> 16) & 1u)) >> 16;
}

// cardinal cubic B-spline on uniform knots h=2/11; t=tanh(x) in (-1,1).
// Returns the 8 basis slots as 16B (4xu32 of packed bf16): weights w0..w3
// land at slots c-3..c (out-of-range slots dropped), rest zero.
__device__ __forceinline__ void basis_slots(float xv, uint32_t o[4]) {
  xv = fminf(15.f, fmaxf(-15.f, xv));
  float e  = __expf(2.0f * xv);
  float t  = (e - 1.0f) * __builtin_amdgcn_rcpf(e + 1.0f);
  float uf = (t + 1.0f) * 5.5f;            // /h
  int   c  = (int)uf;  c = c > 10 ? 10 : c;
  float u  = uf - (float)c;
  float u2 = u * u, u3 = u2 * u, om = 1.0f - u;
  float w0 = om * om * om * (1.0f / 6.0f);
  float w1 = (3.0f * u3 - 6.0f * u2 + 4.0f) * (1.0f / 6.0f);
  float w2 = (-3.0f * u3 + 3.0f * u2 + 3.0f * u + 1.0f) * (1.0f / 6.0f);
  float w3 = u3 * (1.0f / 6.0f);
  uint32_t p01 = f2bf(w0) | (f2bf(w1) << 16);
  uint32_t p23 = f2bf(w2) | (f2bf(w3) << 16);
  uint64_t W = (uint64_t)p01 | ((uint64_t)p23 << 32);
  int d = c - 3;                            // slot of w0, in [-3, 7]
  uint64_t lo = (d < 0) ? (W >> ((-d) * 16))
              : ((d < 4) ? (W << (d * 16)) : 0ull);
  uint64_t hi = (d <= 0) ? 0ull
              : ((d < 4) ? (W >> ((4 - d) * 16)) : (W << ((d - 4) * 16)));
  o[0] = (uint32_t)lo; o[1] = (uint32_t)(lo >> 32);
  o[2] = (uint32_t)hi; o[3] = (uint32_t)(hi >> 32);
}

// ---------------- coeff cast: [512][512][8] fp32 -> bf16 (== B^T[512][4096]) --
__global__ __launch_bounds__(256) void cvt_kernel(const float* __restrict__ c,
                                                  __hip_bfloat16* __restrict__ Bt,
                                                  int total8) {
  int idx = blockIdx.x * 256 + threadIdx.x;
  if (idx >= total8) return;
  const float4* cp = reinterpret_cast<const float4*>(c) + (size_t)idx * 2;
  float4 a = cp[0], b = cp[1];
  union { unsigned short us[8]; int4 v; } pk;
  pk.us[0] = f2bf(a.x); pk.us[1] = f2bf(a.y);
  pk.us[2] = f2bf(a.z); pk.us[3] = f2bf(a.w);
  pk.us[4] = f2bf(b.x); pk.us[5] = f2bf(b.y);
  pk.us[6] = f2bf(b.z); pk.us[7] = f2bf(b.w);
  reinterpret_cast<int4*>(Bt)[idx] = pk.v;
}

// ---------------- fused basis + GEMM ----------------------------------------
__global__ __launch_bounds__(512, 2) void fused_kernel(
    const float* __restrict__ x,            // [8192][512]
    const __hip_bfloat16* __restrict__ Bt,  // [512][4096]
    float* __restrict__ C) {                // [8192][512]
  __shared__ char lds[2 * GRP_LDS];         // 128 KB

  const int tid   = threadIdx.x;
  const int wid   = tid >> 6;
  const int lane  = tid & 63;
  const int quad  = lane >> 4;
  const int l16   = lane & 15;
  const int kgrp  = wid >> 2;               // 0..1: K-half
  const int w2    = wid & 3;
  const int waveM = w2 >> 1, waveN = w2 & 1;
  const int tg    = tid & 255;              // thread-in-group

  // XCD-aware decode: 4 N-blocks of an M-stripe share one XCD's L2 (x rows).
  int b = blockIdx.x;
  int mt = (b & 7) * 8 + ((b >> 3) >> 2);
  int nt = (b >> 3) & 3;
  const int m0 = mt * BM, n0 = nt * BN;

  char* grp = lds + kgrp * GRP_LDS;

  // staging descriptors: slot s -> (row, phys chunk p), src chunk = p^(row&7)
  uint32_t bGlob[4], sOff[4], xBase[4], aWr[4];
#pragma unroll
  for (int t = 0; t < 4; ++t) {
    int s = t * 256 + tg, row = s >> 3, p = s & 7;
    sOff[t]  = (uint32_t)s * 16u;
    bGlob[t] = (uint32_t)(n0 + row) * K_DIM + (uint32_t)(p ^ (row & 7)) * 8u
             + (uint32_t)kgrp * 2048u;
    xBase[t] = (uint32_t)(m0 + row) * 512u + (uint32_t)kgrp * 256u + (uint32_t)p;
    aWr[t]   = (uint32_t)(row * 8 + (p ^ (row & 7))) * 16u;
  }

  // fragment read offsets within a buffer (A at +0, B at +16KB)
  uint32_t aOff[2][4], bOff[2][4];
#pragma unroll
  for (int kk = 0; kk < 2; ++kk) {
    int c = kk * 4 + quad;
#pragma unroll
    for (int mi = 0; mi < 4; ++mi) {
      int row = waveM * 64 + mi * 16 + l16;
      aOff[kk][mi] = (uint32_t)(row * 8 + (c ^ (row & 7))) * 16u;
    }
#pragma unroll
    for (int ni = 0; ni < 4; ++ni) {
      int row = waveN * 64 + ni * 16 + l16;
      bOff[kk][ni] = 16384u + (uint32_t)(row * 8 + (c ^ (row & 7))) * 16u;
    }
  }

  f32x4 acc[4][4];
#pragma unroll
  for (int mi = 0; mi < 4; ++mi)
#pragma unroll
    for (int ni = 0; ni < 4; ++ni)
      acc[mi][ni] = (f32x4){0.f, 0.f, 0.f, 0.f};

  // prologue: tile 0 into buffer 0 (B via async gload, A via compute+ds_write)
#pragma unroll
  for (int t = 0; t < 4; ++t)
    gload_lds16(Bt + bGlob[t], grp + 16384 + sOff[t]);
#pragma unroll
  for (int t = 0; t < 4; ++t) {
    uint32_t o[4]; basis_slots(x[xBase[t]], o);
    *reinterpret_cast<int4*>(grp + aWr[t]) = make_int4(o[0], o[1], o[2], o[3]);
  }

  for (int it = 0; it < NT_HALF; ++it) {
    const int cur = it & 1;
    char* bufc = grp + cur * BUF_HALF;
    __syncthreads();                        // drains gloads + ds_writes for cur
    if (it + 1 < NT_HALF) {
      char* bufn = grp + (1 - cur) * BUF_HALF;
      uint32_t kOff = (uint32_t)(it + 1) * 64u;
#pragma unroll
      for (int t = 0; t < 4; ++t)
        gload_lds16(Bt + bGlob[t] + kOff, bufn + 16384 + sOff[t]);
#pragma unroll
      for (int t = 0; t < 4; ++t) {
        uint32_t o[4]; basis_slots(x[xBase[t] + (uint32_t)(it + 1) * 8u], o);
        *reinterpret_cast<int4*>(bufn + aWr[t]) = make_int4(o[0], o[1], o[2], o[3]);
      }
    }
#pragma unroll
    for (int kk = 0; kk < 2; ++kk) {
      short8 af[4], bf[4];
#pragma unroll
      for (int mi = 0; mi < 4; ++mi)
        af[mi] = *reinterpret_cast<const short8*>(bufc + aOff[kk][mi]);
#pragma unroll
      for (int ni = 0; ni < 4; ++ni)
        bf[ni] = *reinterpret_cast<const short8*>(bufc + bOff[kk][ni]);
#pragma unroll
      for (int mi = 0; mi < 4; ++mi)
#pragma unroll
        for (int ni = 0; ni < 4; ++ni)
          acc[mi][ni] = __builtin_amdgcn_mfma_f32_16x16x32_bf16(
              af[mi], bf[ni], acc[mi][ni], 0, 0, 0);
    }
  }

  // split-K reduction: group 1 parks partials in [0,64KB), group 0 sums+stores
  __syncthreads();
  if (kgrp == 1) {
#pragma unroll
    for (int mi = 0; mi < 4; ++mi)
#pragma unroll
      for (int ni = 0; ni < 4; ++ni) {
        int f = mi * 4 + ni;
        *reinterpret_cast<f32x4*>(lds + w2 * 16384 + f * 1024 + lane * 16) =
            acc[mi][ni];
      }
  }
  __syncthreads();
  if (kgrp == 0) {
#pragma unroll
    for (int mi = 0; mi < 4; ++mi) {
#pragma unroll
      for (int ni = 0; ni < 4; ++ni) {
        int f = mi * 4 + ni;
        f32x4 other = *reinterpret_cast<f32x4*>(
            lds + w2 * 16384 + f * 1024 + lane * 16);
        f32x4 s = acc[mi][ni] + other;
        int col = n0 + waveN * 64 + ni * 16 + l16;
#pragma unroll
        for (int r = 0; r < 4; ++r) {
          int row = m0 + waveM * 64 + mi * 16 + quad * 4 + r;
          C[(size_t)row * N_DIM + col] = s[r];   // m89/m91 C/D layout
        }
      }
    }
  }
}

extern "C" void kernel_launch(void* const* d_in, const int* in_sizes, int n_in,
                              void* d_out, int out_size, void* d_ws, size_t ws_size,
                              hipStream_t stream) {
  const float* x    = (const float*)d_in[0];   // [8192,512]
  const float* coef = (const float*)d_in[1];   // [512,512,8]
  float* out = (float*)d_out;                  // [8192,512]

  __hip_bfloat16* Bt = (__hip_bfloat16*)d_ws;  // 4 MB only

  const int total8 = N_DIM * K_DIM / 8;        // 262144
  cvt_kernel<<<(total8 + 255) / 256, 256, 0, stream>>>(coef, Bt, total8);

  fused_kernel<<<(M_TOTAL / BM) * (N_DIM / BN), 512, 0, stream>>>(x, Bt, out);
}